// Round 10
// baseline (323.136 us; speedup 1.0000x reference)
//
#include <hip/hip_runtime.h>

// SharedSparseMoEBlock on gfx950 — round 21.
// State: r17/r20 best = 321-322us reproduced; moe frozen (187us, all levers
// ledgered null); aux pipeline = ~135us, opaque (top-5 rows all moe).
// r21 probes the largest aux candidate: final_add. It gathers 64 RANDOM 256B
// outT rows per block (pixslot scatter -> L2/L3 latency) with grid 1152 =
// 4.5 blocks/CU (grid-limited; LDS/VGPR would allow ~8+). Split over channels:
// grid 2304, 64px x 64ch per block, LDS 8.8KB, same coalescing -> ~9 blocks/CU
// = 2x latency-hiding TLP. router/fill_bins/moe byte-identical to r20.
// Also a measurement: delta bounds final_add's true cost.
// Sentinels: moe ~187us/VGPR80/WRITE 18,848KB; absmax 0.03125.

typedef __bf16 bf16x8 __attribute__((ext_vector_type(8)));
typedef __bf16 bf16x2 __attribute__((ext_vector_type(2)));
typedef unsigned short u16x8 __attribute__((ext_vector_type(8)));
typedef float f32x4 __attribute__((ext_vector_type(4)));

#define HWP 9216
#define NPIX 73728
#define LDX 136
#define LDH 136
#define LXP 68         // xls f32 pitch (17 banks: conflict-benign, 16B-aligned)
#define MAXSLOTS 77312
#define MAXTILES 1208
#define NSH 16         // atomic shadow copies

__device__ __forceinline__ unsigned short f2bf(float f) {
    return __builtin_bit_cast(unsigned short, (__bf16)f);   // HW RNE cast
}

__device__ __forceinline__ unsigned pk_bf16(float a, float b) {
    bf16x2 v; v[0] = (__bf16)a; v[1] = (__bf16)b;           // -> v_cvt_pk_bf16_f32
    return __builtin_bit_cast(unsigned, v);
}

__device__ __forceinline__ float bf2f(unsigned short h) {
    return __uint_as_float((unsigned)h << 16);
}

__device__ __forceinline__ float fast_gelu(float x) {
    float x2 = x * x;
    float u = x * fmaf(0.0356774081f, x2, 0.7978845608f);
    float e = __builtin_amdgcn_exp2f(u * 2.8853900818f);
    float r = __builtin_amdgcn_rcpf(e + 1.0f);
    float t = fmaf(-2.0f, r, 1.0f);
    float s = 0.5f * x;
    return fmaf(s, t, s);
}

__device__ __forceinline__ f32x4 mfma16(u16x8 a, u16x8 b, f32x4 c) {
    return __builtin_amdgcn_mfma_f32_16x16x32_bf16(
        __builtin_bit_cast(bf16x8, a), __builtin_bit_cast(bf16x8, b), c, 0, 0, 0);
}

// router + weight convert + xT write. Staging via wide coalesced loads.
__global__ __launch_bounds__(256) void router_fused(
    const float* __restrict__ x, const float* __restrict__ gw,
    const float* __restrict__ gb,
    const float* __restrict__ sw1, const float* __restrict__ sw2,
    const float* __restrict__ ew1, const float* __restrict__ ew2,
    unsigned short* __restrict__ wbf,
    unsigned short* __restrict__ xT,
    int* __restrict__ pixmask, float* __restrict__ pixw3,
    int* __restrict__ pixaux,
    int* __restrict__ bincount, float* __restrict__ accum)
{
    __shared__ float gws[1024];
    __shared__ float xls[128 * LXP];          // f32 [channel][pixel]
    __shared__ float part[4 * 64 * 8];

    const int tid = threadIdx.x;
    const int blk = blockIdx.x;               // grid = 1152
    const int shadow = blk & (NSH - 1);

    {   // weight conversion: 4 elems/thread
        int i = blk * 256 + tid;
        #pragma unroll
        for (int j = 0; j < 4; ++j) {
            float v;
            if (i < 65536) v = sw1[i];
            else if (i < 131072) v = sw2[i - 65536];
            else if (i < 655360) v = ew1[i - 131072];
            else v = ew2[i - 655360];
            wbf[i] = f2bf(v);
            i += 1152 * 256;
        }
    }

    for (int i = tid; i < 1024; i += 256) gws[i] = gw[i];

    const int b = blk / 144;
    const int p0 = (blk - b * 144) * 64;
    const float* xb = x + (size_t)b * 128 * HWP + p0;

    // stage x: 8 independent f32x4 loads/thread, coalesced per wave
    #pragma unroll
    for (int j = 0; j < 8; ++j) {
        int id4 = j * 256 + tid;              // 2048 vec4 slots = 128c x 16g
        int c = id4 >> 4;
        int g = id4 & 15;
        f32x4 v = *(const f32x4*)(xb + (size_t)c * HWP + g * 4);
        *(f32x4*)&xls[c * LXP + g * 4] = v;
    }
    __syncthreads();

    // partial logits: wave q covers channels q*32..+31, lane p = pixel
    const int p = tid & 63, q = tid >> 6;
    {
        float lg[8];
        #pragma unroll
        for (int e = 0; e < 8; ++e) lg[e] = 0.f;
        #pragma unroll
        for (int k = 0; k < 32; ++k) {
            int c = q * 32 + k;
            float xv = xls[c * LXP + p];
            #pragma unroll
            for (int e = 0; e < 8; ++e) lg[e] = fmaf(xv, gws[e * 128 + c], lg[e]);
        }
        #pragma unroll
        for (int e = 0; e < 8; ++e) part[(q * 64 + p) * 8 + e] = lg[e];
    }
    __syncthreads();

    if (tid < 64) {                            // wave 0: one pixel per lane
        const int gp = b * HWP + p0 + tid;
        float l2[8];
        #pragma unroll
        for (int e = 0; e < 8; ++e)
            l2[e] = gb[e] + part[tid * 8 + e] + part[(64 + tid) * 8 + e]
                  + part[(128 + tid) * 8 + e] + part[(192 + tid) * 8 + e];
        float mx = l2[0];
        #pragma unroll
        for (int e = 1; e < 8; ++e) mx = fmaxf(mx, l2[e]);
        float pr[8]; float s = 0.f;
        #pragma unroll
        for (int e = 0; e < 8; ++e) { pr[e] = __expf(l2[e] - mx); s += pr[e]; }
        float sinv = __builtin_amdgcn_rcpf(s);
        #pragma unroll
        for (int e = 0; e < 8; ++e) pr[e] *= sinv;

        // top-3, first-index wins ties (matches lax.top_k)
        unsigned chosen = 0; float topsum = 0.f;
        for (int k = 0; k < 3; ++k) {
            int best = 0; float bv = -1.f;
            #pragma unroll
            for (int e = 0; e < 8; ++e) {
                bool ok = !((chosen >> e) & 1u) && pr[e] > bv;
                bv = ok ? pr[e] : bv;
                best = ok ? e : best;
            }
            chosen |= 1u << best;
            topsum += bv;
        }
        float tinv = __builtin_amdgcn_rcpf(topsum);

        pixmask[gp] = (int)chosen;
        {
            int j = 0;
            #pragma unroll
            for (int e = 0; e < 8; ++e)
                if ((chosen >> e) & 1u) { pixw3[gp * 3 + j] = pr[e] * tinv; ++j; }
        }

        // ballot equality-classes -> one shadowed atomic per class
        unsigned long long eq = ~0ull;
        #pragma unroll
        for (int bit = 0; bit < 8; ++bit) {
            unsigned long long bb = __ballot((chosen >> bit) & 1u);
            eq &= ((chosen >> bit) & 1u) ? bb : ~bb;
        }
        const unsigned long long lowmask = (tid == 0) ? 0ull : (~0ull >> (64 - tid));
        int rank = __popcll(eq & lowmask);
        int cnt = __popcll(eq);
        int leader = __ffsll((unsigned long long)eq) - 1;
        int off_val = 0;
        if (rank == 0) off_val = atomicAdd(&bincount[shadow * 256 + (int)chosen], cnt);
        int binoff = __shfl(off_val, leader);
        pixaux[gp] = binoff + rank;            // position within (shadow, bin)

        // aux: shuffle reduce, lane 0 -> 16 shadowed atomics
        #pragma unroll
        for (int e = 0; e < 8; ++e) {
            float v = pr[e];
            float c2 = ((chosen >> e) & 1u) ? 1.f : 0.f;
            #pragma unroll
            for (int off = 32; off > 0; off >>= 1) {
                v += __shfl_down(v, off);
                c2 += __shfl_down(c2, off);
            }
            if (tid == 0) {
                atomicAdd(&accum[shadow * 16 + e], v);
                atomicAdd(&accum[shadow * 16 + 8 + e], c2);
            }
        }
    }

    // xT write: pixel pp, channel quarter qq; xls read-only since staging barrier
    {
        const int pp = tid >> 2, qq = tid & 3;
        unsigned short* dst = xT + ((size_t)(blk * 64 + pp)) * 128 + qq * 32;
        #pragma unroll
        for (int j = 0; j < 4; ++j) {
            const int c0 = qq * 32 + j * 8;
            uint4 wv;
            wv.x = pk_bf16(xls[(c0 + 0) * LXP + pp], xls[(c0 + 1) * LXP + pp]);
            wv.y = pk_bf16(xls[(c0 + 2) * LXP + pp], xls[(c0 + 3) * LXP + pp]);
            wv.z = pk_bf16(xls[(c0 + 4) * LXP + pp], xls[(c0 + 5) * LXP + pp]);
            wv.w = pk_bf16(xls[(c0 + 6) * LXP + pp], xls[(c0 + 7) * LXP + pp]);
            *(uint4*)(dst + j * 8) = wv;
        }
    }
}

// scan + fill with shadow folding
__global__ __launch_bounds__(256) void fill_bins(
    const int* __restrict__ bincount, const int* __restrict__ pixmask,
    int* __restrict__ idx, int* __restrict__ pixaux,
    int* __restrict__ tileMask, int* __restrict__ tileBase,
    int* __restrict__ ntiles)
{
    __shared__ int spc[256], snt[256], bb[256];
    __shared__ int sbase[NSH][256];
    const int tid = threadIdx.x;
    int c = 0;
    #pragma unroll
    for (int s = 0; s < NSH; ++s) {
        sbase[s][tid] = c;
        c += bincount[s * 256 + tid];       // coalesced per s
    }
    const int nt = (c + 63) >> 6;
    const int pc = nt << 6;
    spc[tid] = pc; snt[tid] = nt;
    __syncthreads();
    #pragma unroll
    for (int off = 1; off < 256; off <<= 1) {
        int a = (tid >= off) ? spc[tid - off] : 0;
        int d = (tid >= off) ? snt[tid - off] : 0;
        __syncthreads();
        spc[tid] += a; snt[tid] += d;
        __syncthreads();
    }
    const int base = spc[tid] - pc;
    bb[tid] = base;
    if (blockIdx.x == 0) {
        const int tstart = snt[tid] - nt;
        for (int j = 0; j < nt; ++j) {
            tileMask[tstart + j] = tid;
            tileBase[tstart + j] = base + (j << 6);
        }
        if (tid == 255) ntiles[0] = snt[255];
    }
    __syncthreads();

    const int gp = blockIdx.x * 256 + tid;   // grid exactly 73728
    int mask = pixmask[gp];
    int shadow = (gp >> 6) & (NSH - 1);      // router block = gp/64
    int slot = bb[mask] + sbase[shadow][mask] + pixaux[gp];
    idx[slot] = gp;
    pixaux[gp] = slot;                        // reuse as pixslot
}

// moe r17-exact (best known: 188us): wtv folded into h, fin-accumulate across
// passes, closed-form bias epilogue, single hs, 2 barriers/chunk, w2f-early,
// setprio. FROZEN.
__global__ __launch_bounds__(256, 3) void moe_sparse(
    const unsigned short* __restrict__ xT, const int* __restrict__ idx,
    const float* __restrict__ pixw3,
    const int* __restrict__ tileMask, const int* __restrict__ tileBase,
    const int* __restrict__ ntiles,
    const unsigned short* __restrict__ wbf,
    const float* __restrict__ sb1, const float* __restrict__ sb2,
    const float* __restrict__ eb1, const float* __restrict__ eb2,
    unsigned short* __restrict__ outT)
{
    __shared__ unsigned short xs[64 * LDX];
    __shared__ unsigned short hs[64 * LDH];
    __shared__ float wls[64 * 4];

    const int t = blockIdx.x;
    if (t >= ntiles[0]) return;
    const int mask = tileMask[t];
    const int base = tileBase[t];
    const int tid = threadIdx.x;

    {
        const int p = tid >> 2, q = tid & 3;
        const int gp = idx[base + p];
        const unsigned short* src = xT + (size_t)gp * 128 + q * 32;
        unsigned short* dst = &xs[p * LDX + q * 32];
        #pragma unroll
        for (int j = 0; j < 4; ++j)
            *(u16x8*)(dst + j * 8) = *(const u16x8*)(src + j * 8);
        if (q == 0) {
            wls[p * 4 + 0] = pixw3[gp * 3 + 0];
            wls[p * 4 + 1] = pixw3[gp * 3 + 1];
            wls[p * 4 + 2] = pixw3[gp * 3 + 2];
        }
    }
    __syncthreads();

    int el[3];
    { int n = 0;
      #pragma unroll
      for (int e = 0; e < 8; ++e) if ((mask >> e) & 1) { if (n < 3) el[n] = e; ++n; } }

    const int wave = tid >> 6;
    const int lr = tid & 15;
    const int lq = (tid >> 4) & 3;

    const f32x4 vzero = {0.f, 0.f, 0.f, 0.f};
    f32x4 fin[2][4];                 // GEMM2 accumulator across ALL passes
    #pragma unroll
    for (int t2 = 0; t2 < 2; ++t2)
        #pragma unroll
        for (int nt2 = 0; nt2 < 4; ++nt2) fin[t2][nt2] = vzero;

    for (int pass = 0; pass < 4; ++pass) {
        const unsigned short* w1; const unsigned short* w2;
        const float* b1;
        if (pass == 0) { w1 = wbf; b1 = sb1; w2 = wbf + 65536; }
        else {
            int e = el[pass - 1];
            w1 = wbf + 131072 + (size_t)e * (512 * 128);  b1 = eb1 + e * 512;
            w2 = wbf + 655360 + (size_t)e * (128 * 512);
        }

        // per-pixel routing weight for this pass (folded into h)
        float wtv[4];
        #pragma unroll
        for (int nt2 = 0; nt2 < 4; ++nt2)
            wtv[nt2] = (pass == 0) ? 1.0f : wls[(nt2 * 16 + lr) * 4 + (pass - 1)];

        for (int chunk = 0; chunk < 4; ++chunk) {
            u16x8 w1f[2][4];
            #pragma unroll
            for (int t2 = 0; t2 < 2; ++t2) {
                const int hid0 = chunk * 128 + wave * 32 + t2 * 16;
                const u16x8* wr = (const u16x8*)(w1 + (size_t)(hid0 + lr) * 128) + lq;
                #pragma unroll
                for (int ks = 0; ks < 4; ++ks) w1f[t2][ks] = wr[ks * 4];
            }
            f32x4 acc[2][4];
            #pragma unroll
            for (int t2 = 0; t2 < 2; ++t2)
                #pragma unroll
                for (int nt2 = 0; nt2 < 4; ++nt2) acc[t2][nt2] = vzero;
            __builtin_amdgcn_s_setprio(1);
            #pragma unroll
            for (int ks = 0; ks < 4; ++ks) {
                #pragma unroll
                for (int nt2 = 0; nt2 < 4; ++nt2) {
                    u16x8 xf = *(const u16x8*)&xs[(nt2 * 16 + lr) * LDX + ks * 32 + lq * 8];
                    acc[0][nt2] = mfma16(w1f[0][ks], xf, acc[0][nt2]);
                    acc[1][nt2] = mfma16(w1f[1][ks], xf, acc[1][nt2]);
                }
            }
            __builtin_amdgcn_s_setprio(0);

            // issue-early: w2f loads (w1f just died -> net-zero peak regs)
            u16x8 w2f[2][4];
            #pragma unroll
            for (int t2 = 0; t2 < 2; ++t2) {
                const int c0 = wave * 32 + t2 * 16;
                const u16x8* wr = (const u16x8*)(w2 + (size_t)(c0 + lr) * 512 + chunk * 128) + lq;
                #pragma unroll
                for (int ks = 0; ks < 4; ++ks) w2f[t2][ks] = wr[ks * 4];
            }

            // gelu + bias, pre-scaled by wtv (lane col == pixel), -> hs
            #pragma unroll
            for (int t2 = 0; t2 < 2; ++t2) {
                const int hl = wave * 32 + t2 * 16 + lq * 4;
                const f32x4 b1v = *(const f32x4*)&b1[chunk * 128 + hl];
                #pragma unroll
                for (int nt2 = 0; nt2 < 4; ++nt2) {
                    float g0 = wtv[nt2] * fast_gelu(acc[t2][nt2][0] + b1v[0]);
                    float g1 = wtv[nt2] * fast_gelu(acc[t2][nt2][1] + b1v[1]);
                    float g2 = wtv[nt2] * fast_gelu(acc[t2][nt2][2] + b1v[2]);
                    float g3 = wtv[nt2] * fast_gelu(acc[t2][nt2][3] + b1v[3]);
                    uint2 wv = {pk_bf16(g0, g1), pk_bf16(g2, g3)};
                    *(uint2*)&hs[(nt2 * 16 + lr) * LDH + hl] = wv;
                }
            }
            __syncthreads();
            __builtin_amdgcn_s_setprio(1);
            #pragma unroll
            for (int ks = 0; ks < 4; ++ks) {
                #pragma unroll
                for (int nt2 = 0; nt2 < 4; ++nt2) {
                    u16x8 hb = *(const u16x8*)&hs[(nt2 * 16 + lr) * LDH + ks * 32 + lq * 8];
                    fin[0][nt2] = mfma16(w2f[0][ks], hb, fin[0][nt2]);
                    fin[1][nt2] = mfma16(w2f[1][ks], hb, fin[1][nt2]);
                }
            }
            __builtin_amdgcn_s_setprio(0);
            __syncthreads();
        }
    }

    // epilogue: bias = sb2 + sum_k wls_k * eb2[el_k]  (exact closed form)
    #pragma unroll
    for (int t2 = 0; t2 < 2; ++t2) {
        const int cidx = wave * 32 + t2 * 16 + lq * 4;
        const f32x4 s2v = *(const f32x4*)&sb2[cidx];
        const f32x4 e0v = *(const f32x4*)&eb2[el[0] * 128 + cidx];
        const f32x4 e1v = *(const f32x4*)&eb2[el[1] * 128 + cidx];
        const f32x4 e2v = *(const f32x4*)&eb2[el[2] * 128 + cidx];
        #pragma unroll
        for (int nt2 = 0; nt2 < 4; ++nt2) {
            const float w0 = wls[(nt2 * 16 + lr) * 4 + 0];
            const float w1 = wls[(nt2 * 16 + lr) * 4 + 1];
            const float w2 = wls[(nt2 * 16 + lr) * 4 + 2];
            float o[4];
            #pragma unroll
            for (int r = 0; r < 4; ++r) {
                float bsum = s2v[r];
                bsum = fmaf(w0, e0v[r], bsum);
                bsum = fmaf(w1, e1v[r], bsum);
                bsum = fmaf(w2, e2v[r], bsum);
                o[r] = fin[t2][nt2][r] + bsum;
            }
            unsigned short* dst = outT + ((size_t)(base + nt2 * 16 + lr)) * 128
                                + wave * 32 + t2 * 16 + lq * 4;
            uint2 wv = {pk_bf16(o[0], o[1]), pk_bf16(o[2], o[3])};
            *(uint2*)dst = wv;
        }
    }
}

// r21: channel-split final_add — grid 2304, 64px x 64ch per block.
// More blocks to hide the pixslot-scattered outT gather latency.
__global__ __launch_bounds__(256) void final_add(
    const float* __restrict__ x, const unsigned short* __restrict__ outT,
    const int* __restrict__ pixslot, const float* __restrict__ accum,
    float* __restrict__ out)
{
    if (blockIdx.x == 0 && threadIdx.x == 0) {   // fold shadows + aux loss
        float a16[16];
        #pragma unroll
        for (int i = 0; i < 16; ++i) {
            float s = 0.f;
            #pragma unroll
            for (int sh = 0; sh < NSH; ++sh) s += accum[sh * 16 + i];
            a16[i] = s;
        }
        float aux = 0.f;
        #pragma unroll
        for (int e = 0; e < 8; ++e) aux += a16[e] * a16[8 + e];
        out[9437184] = 8.0f * aux / ((float)NPIX * (float)NPIX);
    }
    __shared__ unsigned short ts[64 * 69];       // 64 px x 64 ch, pitch 69
    const int blk = blockIdx.x;                  // grid = 2304
    const int blk2 = blk >> 1;                   // pixel-group 0..1151
    const int ch0 = (blk & 1) * 64;              // channel half
    const int b = blk2 / 144;
    const int p0 = (blk2 - b * 144) * 64;
    const int tid = threadIdx.x;
    {
        const int p = tid >> 2, q = tid & 3;     // 64 px x 4 seg (16ch each)
        const int slot = pixslot[blk2 * 64 + p];
        const unsigned short* src = outT + (size_t)slot * 128 + ch0 + q * 16;
        unsigned short* dst = &ts[p * 69 + q * 16];
        *(u16x8*)(dst + 0) = *(const u16x8*)(src + 0);
        *(u16x8*)(dst + 8) = *(const u16x8*)(src + 8);
    }
    __syncthreads();
    const int pl = tid & 63, cq = tid >> 6;
    const float* xb = x + (size_t)b * 128 * HWP + p0;
    float* ob = out + (size_t)b * 128 * HWP + p0;
    #pragma unroll
    for (int c0 = 0; c0 < 64; c0 += 4) {
        int cg = c0 + cq;                        // local channel 0..63
        int c = ch0 + cg;                        // global channel
        ob[(size_t)c * HWP + pl] = xb[(size_t)c * HWP + pl] + bf2f(ts[pl * 69 + cg]);
    }
}

extern "C" void kernel_launch(void* const* d_in, const int* in_sizes, int n_in,
                              void* d_out, int out_size, void* d_ws, size_t ws_size,
                              hipStream_t stream)
{
    const float* x   = (const float*)d_in[0];
    const float* sw1 = (const float*)d_in[1];
    const float* sb1 = (const float*)d_in[2];
    const float* sw2 = (const float*)d_in[3];
    const float* sb2 = (const float*)d_in[4];
    const float* gw  = (const float*)d_in[5];
    const float* gb  = (const float*)d_in[6];
    const float* ew1 = (const float*)d_in[7];
    const float* eb1 = (const float*)d_in[8];
    const float* ew2 = (const float*)d_in[9];
    const float* eb2 = (const float*)d_in[10];
    float* out = (float*)d_out;
    char* ws = (char*)d_ws;

    const size_t o_wbf     = 0;                       // 2359296
    const size_t o_xT      = 2359296;                 // 18874368
    const size_t o_outT    = o_xT + 18874368;         // 19791872
    const size_t o_pixmask = o_outT + 19791872;       // 294912
    const size_t o_pixw3   = o_pixmask + 294912;      // 884736
    const size_t o_pixaux  = o_pixw3 + 884736;        // 294912
    const size_t o_tmask   = o_pixaux + 294912;       // 4864
    const size_t o_tbase   = o_tmask + 4864;          // 4864
    const size_t o_idx     = o_tbase + 4864;          // 309248  <-- memset from here
    const size_t o_cnt     = o_idx + 309248;          // NSH*256*4 = 16384
    const size_t o_ntiles  = o_cnt + 16384;           // 16
    const size_t o_accum   = o_ntiles + 16;           // NSH*16*4 = 1024
    const size_t MEMSET_SZ = 309248 + 16384 + 16 + 1024;

    unsigned short* wbf  = (unsigned short*)(ws + o_wbf);
    unsigned short* xT   = (unsigned short*)(ws + o_xT);
    unsigned short* outT = (unsigned short*)(ws + o_outT);
    int* pixmask  = (int*)(ws + o_pixmask);
    float* pixw3  = (float*)(ws + o_pixw3);
    int* pixaux   = (int*)(ws + o_pixaux);
    int* tmask    = (int*)(ws + o_tmask);
    int* tbase    = (int*)(ws + o_tbase);
    int* idx      = (int*)(ws + o_idx);
    int* bincount = (int*)(ws + o_cnt);
    int* ntiles   = (int*)(ws + o_ntiles);
    float* accum  = (float*)(ws + o_accum);

    (void)hipMemsetAsync(ws + o_idx, 0, MEMSET_SZ, stream);
    router_fused<<<1152, 256, 0, stream>>>(x, gw, gb, sw1, sw2, ew1, ew2, wbf,
                                           xT, pixmask, pixw3, pixaux, bincount, accum);
    fill_bins<<<288, 256, 0, stream>>>(bincount, pixmask, idx, pixaux,
                                       tmask, tbase, ntiles);
    moe_sparse<<<MAXTILES, 256, 0, stream>>>(xT, idx, pixw3, tmask, tbase, ntiles,
        wbf, sb1, sb2, eb1, eb2, outT);
    final_add<<<2304, 256, 0, stream>>>(x, outT, pixaux, accum, out);
}

// Round 12
// 274.467 us; speedup vs baseline: 1.1773x; 1.1773x over previous
//
#include <hip/hip_runtime.h>

// SharedSparseMoEBlock on gfx950 — round 23 (resubmit of r22; bench was an
// infra failure with no signal, and the permute audit found no fault).
// Theory under test: moe wall/tile ~286k cyc vs 45k issue. Weight fragment
// loads are 256B-STRIDE GATHERS (lane l reads (hid0+(l&15))*256B): every lane
// a distinct 64B line -> 64 L2 txns/instr -> saturates per-CU TA/TCP request
// pipe. Explains why barriers/latency/setprio/occupancy/TLP were ALL null.
// Fix: wbf re-stored in FRAGMENT-LANE-MAJOR packets (1KB per (h,ks): lane l's
// 16B at base+h*256+ks*64+lane in u16x8 units) -> wave reads 1KB contiguous,
// 4 lanes/64B line merge = 4x fewer txns. Pure layout change: per-lane
// fragment contents bit-identical, register/LDS/barrier structure r20-exact.
// Sentinels: VGPR~80, LDS 35840, WRITE 18,848KB, absmax 0.03125.
// Predict moe 187->120-150us if theory holds; unchanged refutes it.

typedef __bf16 bf16x8 __attribute__((ext_vector_type(8)));
typedef __bf16 bf16x2 __attribute__((ext_vector_type(2)));
typedef unsigned short u16x8 __attribute__((ext_vector_type(8)));
typedef float f32x4 __attribute__((ext_vector_type(4)));

#define HWP 9216
#define NPIX 73728
#define LDX 136
#define LDH 136
#define LXP 68         // xls f32 pitch (17 banks: conflict-benign, 16B-aligned)
#define MAXSLOTS 77312
#define MAXTILES 1208
#define NSH 16         // atomic shadow copies

__device__ __forceinline__ unsigned short f2bf(float f) {
    return __builtin_bit_cast(unsigned short, (__bf16)f);   // HW RNE cast
}

__device__ __forceinline__ unsigned pk_bf16(float a, float b) {
    bf16x2 v; v[0] = (__bf16)a; v[1] = (__bf16)b;           // -> v_cvt_pk_bf16_f32
    return __builtin_bit_cast(unsigned, v);
}

__device__ __forceinline__ float bf2f(unsigned short h) {
    return __uint_as_float((unsigned)h << 16);
}

__device__ __forceinline__ float fast_gelu(float x) {
    float x2 = x * x;
    float u = x * fmaf(0.0356774081f, x2, 0.7978845608f);
    float e = __builtin_amdgcn_exp2f(u * 2.8853900818f);
    float r = __builtin_amdgcn_rcpf(e + 1.0f);
    float t = fmaf(-2.0f, r, 1.0f);
    float s = 0.5f * x;
    return fmaf(s, t, s);
}

__device__ __forceinline__ f32x4 mfma16(u16x8 a, u16x8 b, f32x4 c) {
    return __builtin_amdgcn_mfma_f32_16x16x32_bf16(
        __builtin_bit_cast(bf16x8, a), __builtin_bit_cast(bf16x8, b), c, 0, 0, 0);
}

// router + weight convert (fragment-lane-major permute) + xT write.
__global__ __launch_bounds__(256) void router_fused(
    const float* __restrict__ x, const float* __restrict__ gw,
    const float* __restrict__ gb,
    const float* __restrict__ sw1, const float* __restrict__ sw2,
    const float* __restrict__ ew1, const float* __restrict__ ew2,
    unsigned short* __restrict__ wbf,
    unsigned short* __restrict__ xT,
    int* __restrict__ pixmask, float* __restrict__ pixw3,
    int* __restrict__ pixaux,
    int* __restrict__ bincount, float* __restrict__ accum)
{
    __shared__ float gws[1024];
    __shared__ float xls[128 * LXP];          // f32 [channel][pixel]
    __shared__ float part[4 * 64 * 8];

    const int tid = threadIdx.x;
    const int blk = blockIdx.x;               // grid = 1152
    const int shadow = blk & (NSH - 1);

    {   // weight conversion: 4 elems/thread, dest enumerated in NEW layout.
        // w1-type (512x128): n = ((h*4+ks)*64+l)*8+e -> old (h*16+(l&15), ks*32+(l>>4)*8+e)
        // w2-type (128x512): n = ((g*16+ck)*64+l)*8+e -> old (g*16+(l&15), (ck>>2)*128+(ck&3)*32+(l>>4)*8+e)
        int n = blk * 256 + tid;
        #pragma unroll
        for (int j = 0; j < 4; ++j) {
            float v;
            if (n < 65536) {
                int h = n >> 11, r = n & 2047;
                int ks = r >> 9, l = (r >> 3) & 63, e = r & 7;
                v = sw1[(h * 16 + (l & 15)) * 128 + ks * 32 + (l >> 4) * 8 + e];
            } else if (n < 131072) {
                int m = n - 65536;
                int g = m >> 13, r = m & 8191;
                int ck = r >> 9, l = (r >> 3) & 63, e = r & 7;
                v = sw2[(g * 16 + (l & 15)) * 512 + (ck >> 2) * 128 + (ck & 3) * 32
                        + (l >> 4) * 8 + e];
            } else if (n < 655360) {
                int m = n - 131072;
                int ex = m >> 16, r2 = m & 65535;
                int h = r2 >> 11, r = r2 & 2047;
                int ks = r >> 9, l = (r >> 3) & 63, e = r & 7;
                v = ew1[ex * 65536 + (h * 16 + (l & 15)) * 128 + ks * 32
                        + (l >> 4) * 8 + e];
            } else {
                int m = n - 655360;
                int ex = m >> 16, r2 = m & 65535;
                int g = r2 >> 13, r = r2 & 8191;
                int ck = r >> 9, l = (r >> 3) & 63, e = r & 7;
                v = ew2[ex * 65536 + (g * 16 + (l & 15)) * 512 + (ck >> 2) * 128
                        + (ck & 3) * 32 + (l >> 4) * 8 + e];
            }
            wbf[n] = f2bf(v);
            n += 1152 * 256;
        }
    }

    for (int i = tid; i < 1024; i += 256) gws[i] = gw[i];

    const int b = blk / 144;
    const int p0 = (blk - b * 144) * 64;
    const float* xb = x + (size_t)b * 128 * HWP + p0;

    // stage x: 8 independent f32x4 loads/thread, coalesced per wave
    #pragma unroll
    for (int j = 0; j < 8; ++j) {
        int id4 = j * 256 + tid;              // 2048 vec4 slots = 128c x 16g
        int c = id4 >> 4;
        int g = id4 & 15;
        f32x4 v = *(const f32x4*)(xb + (size_t)c * HWP + g * 4);
        *(f32x4*)&xls[c * LXP + g * 4] = v;
    }
    __syncthreads();

    // partial logits: wave q covers channels q*32..+31, lane p = pixel
    const int p = tid & 63, q = tid >> 6;
    {
        float lg[8];
        #pragma unroll
        for (int e = 0; e < 8; ++e) lg[e] = 0.f;
        #pragma unroll
        for (int k = 0; k < 32; ++k) {
            int c = q * 32 + k;
            float xv = xls[c * LXP + p];
            #pragma unroll
            for (int e = 0; e < 8; ++e) lg[e] = fmaf(xv, gws[e * 128 + c], lg[e]);
        }
        #pragma unroll
        for (int e = 0; e < 8; ++e) part[(q * 64 + p) * 8 + e] = lg[e];
    }
    __syncthreads();

    if (tid < 64) {                            // wave 0: one pixel per lane
        const int gp = b * HWP + p0 + tid;
        float l2[8];
        #pragma unroll
        for (int e = 0; e < 8; ++e)
            l2[e] = gb[e] + part[tid * 8 + e] + part[(64 + tid) * 8 + e]
                  + part[(128 + tid) * 8 + e] + part[(192 + tid) * 8 + e];
        float mx = l2[0];
        #pragma unroll
        for (int e = 1; e < 8; ++e) mx = fmaxf(mx, l2[e]);
        float pr[8]; float s = 0.f;
        #pragma unroll
        for (int e = 0; e < 8; ++e) { pr[e] = __expf(l2[e] - mx); s += pr[e]; }
        float sinv = __builtin_amdgcn_rcpf(s);
        #pragma unroll
        for (int e = 0; e < 8; ++e) pr[e] *= sinv;

        // top-3, first-index wins ties (matches lax.top_k)
        unsigned chosen = 0; float topsum = 0.f;
        for (int k = 0; k < 3; ++k) {
            int best = 0; float bv = -1.f;
            #pragma unroll
            for (int e = 0; e < 8; ++e) {
                bool ok = !((chosen >> e) & 1u) && pr[e] > bv;
                bv = ok ? pr[e] : bv;
                best = ok ? e : best;
            }
            chosen |= 1u << best;
            topsum += bv;
        }
        float tinv = __builtin_amdgcn_rcpf(topsum);

        pixmask[gp] = (int)chosen;
        {
            int j = 0;
            #pragma unroll
            for (int e = 0; e < 8; ++e)
                if ((chosen >> e) & 1u) { pixw3[gp * 3 + j] = pr[e] * tinv; ++j; }
        }

        // ballot equality-classes -> one shadowed atomic per class
        unsigned long long eq = ~0ull;
        #pragma unroll
        for (int bit = 0; bit < 8; ++bit) {
            unsigned long long bb = __ballot((chosen >> bit) & 1u);
            eq &= ((chosen >> bit) & 1u) ? bb : ~bb;
        }
        const unsigned long long lowmask = (tid == 0) ? 0ull : (~0ull >> (64 - tid));
        int rank = __popcll(eq & lowmask);
        int cnt = __popcll(eq);
        int leader = __ffsll((unsigned long long)eq) - 1;
        int off_val = 0;
        if (rank == 0) off_val = atomicAdd(&bincount[shadow * 256 + (int)chosen], cnt);
        int binoff = __shfl(off_val, leader);
        pixaux[gp] = binoff + rank;            // position within (shadow, bin)

        // aux: shuffle reduce, lane 0 -> 16 shadowed atomics
        #pragma unroll
        for (int e = 0; e < 8; ++e) {
            float v = pr[e];
            float c2 = ((chosen >> e) & 1u) ? 1.f : 0.f;
            #pragma unroll
            for (int off = 32; off > 0; off >>= 1) {
                v += __shfl_down(v, off);
                c2 += __shfl_down(c2, off);
            }
            if (tid == 0) {
                atomicAdd(&accum[shadow * 16 + e], v);
                atomicAdd(&accum[shadow * 16 + 8 + e], c2);
            }
        }
    }

    // xT write: pixel pp, channel quarter qq; xls read-only since staging barrier
    {
        const int pp = tid >> 2, qq = tid & 3;
        unsigned short* dst = xT + ((size_t)(blk * 64 + pp)) * 128 + qq * 32;
        #pragma unroll
        for (int j = 0; j < 4; ++j) {
            const int c0 = qq * 32 + j * 8;
            uint4 wv;
            wv.x = pk_bf16(xls[(c0 + 0) * LXP + pp], xls[(c0 + 1) * LXP + pp]);
            wv.y = pk_bf16(xls[(c0 + 2) * LXP + pp], xls[(c0 + 3) * LXP + pp]);
            wv.z = pk_bf16(xls[(c0 + 4) * LXP + pp], xls[(c0 + 5) * LXP + pp]);
            wv.w = pk_bf16(xls[(c0 + 6) * LXP + pp], xls[(c0 + 7) * LXP + pp]);
            *(uint4*)(dst + j * 8) = wv;
        }
    }
}

// scan + fill with shadow folding
__global__ __launch_bounds__(256) void fill_bins(
    const int* __restrict__ bincount, const int* __restrict__ pixmask,
    int* __restrict__ idx, int* __restrict__ pixaux,
    int* __restrict__ tileMask, int* __restrict__ tileBase,
    int* __restrict__ ntiles)
{
    __shared__ int spc[256], snt[256], bb[256];
    __shared__ int sbase[NSH][256];
    const int tid = threadIdx.x;
    int c = 0;
    #pragma unroll
    for (int s = 0; s < NSH; ++s) {
        sbase[s][tid] = c;
        c += bincount[s * 256 + tid];       // coalesced per s
    }
    const int nt = (c + 63) >> 6;
    const int pc = nt << 6;
    spc[tid] = pc; snt[tid] = nt;
    __syncthreads();
    #pragma unroll
    for (int off = 1; off < 256; off <<= 1) {
        int a = (tid >= off) ? spc[tid - off] : 0;
        int d = (tid >= off) ? snt[tid - off] : 0;
        __syncthreads();
        spc[tid] += a; snt[tid] += d;
        __syncthreads();
    }
    const int base = spc[tid] - pc;
    bb[tid] = base;
    if (blockIdx.x == 0) {
        const int tstart = snt[tid] - nt;
        for (int j = 0; j < nt; ++j) {
            tileMask[tstart + j] = tid;
            tileBase[tstart + j] = base + (j << 6);
        }
        if (tid == 255) ntiles[0] = snt[255];
    }
    __syncthreads();

    const int gp = blockIdx.x * 256 + tid;   // grid exactly 73728
    int mask = pixmask[gp];
    int shadow = (gp >> 6) & (NSH - 1);      // router block = gp/64
    int slot = bb[mask] + sbase[shadow][mask] + pixaux[gp];
    idx[slot] = gp;
    pixaux[gp] = slot;                        // reuse as pixslot
}

// moe r22: r17 structure with fragment-lane-major weight loads (coalesced 1KB
// per (h,ks) packet). Fragment contents per lane bit-identical to r17.
__global__ __launch_bounds__(256, 3) void moe_sparse(
    const unsigned short* __restrict__ xT, const int* __restrict__ idx,
    const float* __restrict__ pixw3,
    const int* __restrict__ tileMask, const int* __restrict__ tileBase,
    const int* __restrict__ ntiles,
    const unsigned short* __restrict__ wbf,
    const float* __restrict__ sb1, const float* __restrict__ sb2,
    const float* __restrict__ eb1, const float* __restrict__ eb2,
    unsigned short* __restrict__ outT)
{
    __shared__ unsigned short xs[64 * LDX];
    __shared__ unsigned short hs[64 * LDH];
    __shared__ float wls[64 * 4];

    const int t = blockIdx.x;
    if (t >= ntiles[0]) return;
    const int mask = tileMask[t];
    const int base = tileBase[t];
    const int tid = threadIdx.x;

    {
        const int p = tid >> 2, q = tid & 3;
        const int gp = idx[base + p];
        const unsigned short* src = xT + (size_t)gp * 128 + q * 32;
        unsigned short* dst = &xs[p * LDX + q * 32];
        #pragma unroll
        for (int j = 0; j < 4; ++j)
            *(u16x8*)(dst + j * 8) = *(const u16x8*)(src + j * 8);
        if (q == 0) {
            wls[p * 4 + 0] = pixw3[gp * 3 + 0];
            wls[p * 4 + 1] = pixw3[gp * 3 + 1];
            wls[p * 4 + 2] = pixw3[gp * 3 + 2];
        }
    }
    __syncthreads();

    int el[3];
    { int n = 0;
      #pragma unroll
      for (int e = 0; e < 8; ++e) if ((mask >> e) & 1) { if (n < 3) el[n] = e; ++n; } }

    const int wave = tid >> 6;
    const int lane = tid & 63;
    const int lr = tid & 15;
    const int lq = (tid >> 4) & 3;

    const f32x4 vzero = {0.f, 0.f, 0.f, 0.f};
    f32x4 fin[2][4];                 // GEMM2 accumulator across ALL passes
    #pragma unroll
    for (int t2 = 0; t2 < 2; ++t2)
        #pragma unroll
        for (int nt2 = 0; nt2 < 4; ++nt2) fin[t2][nt2] = vzero;

    for (int pass = 0; pass < 4; ++pass) {
        const unsigned short* w1; const unsigned short* w2;
        const float* b1;
        if (pass == 0) { w1 = wbf; b1 = sb1; w2 = wbf + 65536; }
        else {
            int e = el[pass - 1];
            w1 = wbf + 131072 + (size_t)e * 65536;  b1 = eb1 + e * 512;
            w2 = wbf + 655360 + (size_t)e * 65536;
        }

        // per-pixel routing weight for this pass (folded into h)
        float wtv[4];
        #pragma unroll
        for (int nt2 = 0; nt2 < 4; ++nt2)
            wtv[nt2] = (pass == 0) ? 1.0f : wls[(nt2 * 16 + lr) * 4 + (pass - 1)];

        for (int chunk = 0; chunk < 4; ++chunk) {
            // w1f: packet (h = chunk*8 + wave*2 + t2, ks); wave reads 1KB contig
            u16x8 w1f[2][4];
            #pragma unroll
            for (int t2 = 0; t2 < 2; ++t2) {
                const int h = chunk * 8 + wave * 2 + t2;
                const u16x8* wr = (const u16x8*)w1 + (size_t)h * 256 + lane;
                #pragma unroll
                for (int ks = 0; ks < 4; ++ks) w1f[t2][ks] = wr[ks * 64];
            }
            f32x4 acc[2][4];
            #pragma unroll
            for (int t2 = 0; t2 < 2; ++t2)
                #pragma unroll
                for (int nt2 = 0; nt2 < 4; ++nt2) acc[t2][nt2] = vzero;
            __builtin_amdgcn_s_setprio(1);
            #pragma unroll
            for (int ks = 0; ks < 4; ++ks) {
                #pragma unroll
                for (int nt2 = 0; nt2 < 4; ++nt2) {
                    u16x8 xf = *(const u16x8*)&xs[(nt2 * 16 + lr) * LDX + ks * 32 + lq * 8];
                    acc[0][nt2] = mfma16(w1f[0][ks], xf, acc[0][nt2]);
                    acc[1][nt2] = mfma16(w1f[1][ks], xf, acc[1][nt2]);
                }
            }
            __builtin_amdgcn_s_setprio(0);

            // issue-early: w2f packets (g = wave*2 + t2, ck = chunk*4 + ks)
            u16x8 w2f[2][4];
            #pragma unroll
            for (int t2 = 0; t2 < 2; ++t2) {
                const int g = wave * 2 + t2;
                const u16x8* wr = (const u16x8*)w2 + (size_t)(g * 16 + chunk * 4) * 64 + lane;
                #pragma unroll
                for (int ks = 0; ks < 4; ++ks) w2f[t2][ks] = wr[ks * 64];
            }

            // gelu + bias, pre-scaled by wtv (lane col == pixel), -> hs
            #pragma unroll
            for (int t2 = 0; t2 < 2; ++t2) {
                const int hl = wave * 32 + t2 * 16 + lq * 4;
                const f32x4 b1v = *(const f32x4*)&b1[chunk * 128 + hl];
                #pragma unroll
                for (int nt2 = 0; nt2 < 4; ++nt2) {
                    float g0 = wtv[nt2] * fast_gelu(acc[t2][nt2][0] + b1v[0]);
                    float g1 = wtv[nt2] * fast_gelu(acc[t2][nt2][1] + b1v[1]);
                    float g2 = wtv[nt2] * fast_gelu(acc[t2][nt2][2] + b1v[2]);
                    float g3 = wtv[nt2] * fast_gelu(acc[t2][nt2][3] + b1v[3]);
                    uint2 wv = {pk_bf16(g0, g1), pk_bf16(g2, g3)};
                    *(uint2*)&hs[(nt2 * 16 + lr) * LDH + hl] = wv;
                }
            }
            __syncthreads();
            __builtin_amdgcn_s_setprio(1);
            #pragma unroll
            for (int ks = 0; ks < 4; ++ks) {
                #pragma unroll
                for (int nt2 = 0; nt2 < 4; ++nt2) {
                    u16x8 hb = *(const u16x8*)&hs[(nt2 * 16 + lr) * LDH + ks * 32 + lq * 8];
                    fin[0][nt2] = mfma16(w2f[0][ks], hb, fin[0][nt2]);
                    fin[1][nt2] = mfma16(w2f[1][ks], hb, fin[1][nt2]);
                }
            }
            __builtin_amdgcn_s_setprio(0);
            __syncthreads();
        }
    }

    // epilogue: bias = sb2 + sum_k wls_k * eb2[el_k]  (exact closed form)
    #pragma unroll
    for (int t2 = 0; t2 < 2; ++t2) {
        const int cidx = wave * 32 + t2 * 16 + lq * 4;
        const f32x4 s2v = *(const f32x4*)&sb2[cidx];
        const f32x4 e0v = *(const f32x4*)&eb2[el[0] * 128 + cidx];
        const f32x4 e1v = *(const f32x4*)&eb2[el[1] * 128 + cidx];
        const f32x4 e2v = *(const f32x4*)&eb2[el[2] * 128 + cidx];
        #pragma unroll
        for (int nt2 = 0; nt2 < 4; ++nt2) {
            const float w0 = wls[(nt2 * 16 + lr) * 4 + 0];
            const float w1 = wls[(nt2 * 16 + lr) * 4 + 1];
            const float w2 = wls[(nt2 * 16 + lr) * 4 + 2];
            float o[4];
            #pragma unroll
            for (int r = 0; r < 4; ++r) {
                float bsum = s2v[r];
                bsum = fmaf(w0, e0v[r], bsum);
                bsum = fmaf(w1, e1v[r], bsum);
                bsum = fmaf(w2, e2v[r], bsum);
                o[r] = fin[t2][nt2][r] + bsum;
            }
            unsigned short* dst = outT + ((size_t)(base + nt2 * 16 + lr)) * 128
                                + wave * 32 + t2 * 16 + lq * 4;
            uint2 wv = {pk_bf16(o[0], o[1]), pk_bf16(o[2], o[3])};
            *(uint2*)dst = wv;
        }
    }
}

__global__ __launch_bounds__(256) void final_add(
    const float* __restrict__ x, const unsigned short* __restrict__ outT,
    const int* __restrict__ pixslot, const float* __restrict__ accum,
    float* __restrict__ out)
{
    if (blockIdx.x == 0 && threadIdx.x == 0) {   // fold shadows + aux loss
        float a16[16];
        #pragma unroll
        for (int i = 0; i < 16; ++i) {
            float s = 0.f;
            #pragma unroll
            for (int sh = 0; sh < NSH; ++sh) s += accum[sh * 16 + i];
            a16[i] = s;
        }
        float aux = 0.f;
        #pragma unroll
        for (int e = 0; e < 8; ++e) aux += a16[e] * a16[8 + e];
        out[9437184] = 8.0f * aux / ((float)NPIX * (float)NPIX);
    }
    __shared__ unsigned short ts[64 * 133];
    const int blk = blockIdx.x;
    const int b = blk / 144;
    const int p0 = (blk - b * 144) * 64;
    const int tid = threadIdx.x;
    {
        const int p = tid >> 2, q = tid & 3;
        const int slot = pixslot[blk * 64 + p];
        const unsigned short* src = outT + (size_t)slot * 128 + q * 32;
        unsigned short* dst = &ts[p * 133 + q * 32];
        #pragma unroll
        for (int j = 0; j < 4; ++j)
            *(u16x8*)(dst + j * 8) = *(const u16x8*)(src + j * 8);
    }
    __syncthreads();
    const int pl = tid & 63, cq = tid >> 6;
    const float* xb = x + (size_t)b * 128 * HWP + p0;
    float* ob = out + (size_t)b * 128 * HWP + p0;
    #pragma unroll
    for (int c0 = 0; c0 < 128; c0 += 4) {
        int c = c0 + cq;
        ob[(size_t)c * HWP + pl] = xb[(size_t)c * HWP + pl] + bf2f(ts[pl * 133 + c]);
    }
}

extern "C" void kernel_launch(void* const* d_in, const int* in_sizes, int n_in,
                              void* d_out, int out_size, void* d_ws, size_t ws_size,
                              hipStream_t stream)
{
    const float* x   = (const float*)d_in[0];
    const float* sw1 = (const float*)d_in[1];
    const float* sb1 = (const float*)d_in[2];
    const float* sw2 = (const float*)d_in[3];
    const float* sb2 = (const float*)d_in[4];
    const float* gw  = (const float*)d_in[5];
    const float* gb  = (const float*)d_in[6];
    const float* ew1 = (const float*)d_in[7];
    const float* eb1 = (const float*)d_in[8];
    const float* ew2 = (const float*)d_in[9];
    const float* eb2 = (const float*)d_in[10];
    float* out = (float*)d_out;
    char* ws = (char*)d_ws;

    const size_t o_wbf     = 0;                       // 2359296
    const size_t o_xT      = 2359296;                 // 18874368
    const size_t o_outT    = o_xT + 18874368;         // 19791872
    const size_t o_pixmask = o_outT + 19791872;       // 294912
    const size_t o_pixw3   = o_pixmask + 294912;      // 884736
    const size_t o_pixaux  = o_pixw3 + 884736;        // 294912
    const size_t o_tmask   = o_pixaux + 294912;       // 4864
    const size_t o_tbase   = o_tmask + 4864;          // 4864
    const size_t o_idx     = o_tbase + 4864;          // 309248  <-- memset from here
    const size_t o_cnt     = o_idx + 309248;          // NSH*256*4 = 16384
    const size_t o_ntiles  = o_cnt + 16384;           // 16
    const size_t o_accum   = o_ntiles + 16;           // NSH*16*4 = 1024
    const size_t MEMSET_SZ = 309248 + 16384 + 16 + 1024;

    unsigned short* wbf  = (unsigned short*)(ws + o_wbf);
    unsigned short* xT   = (unsigned short*)(ws + o_xT);
    unsigned short* outT = (unsigned short*)(ws + o_outT);
    int* pixmask  = (int*)(ws + o_pixmask);
    float* pixw3  = (float*)(ws + o_pixw3);
    int* pixaux   = (int*)(ws + o_pixaux);
    int* tmask    = (int*)(ws + o_tmask);
    int* tbase    = (int*)(ws + o_tbase);
    int* idx      = (int*)(ws + o_idx);
    int* bincount = (int*)(ws + o_cnt);
    int* ntiles   = (int*)(ws + o_ntiles);
    float* accum  = (float*)(ws + o_accum);

    (void)hipMemsetAsync(ws + o_idx, 0, MEMSET_SZ, stream);
    router_fused<<<1152, 256, 0, stream>>>(x, gw, gb, sw1, sw2, ew1, ew2, wbf,
                                           xT, pixmask, pixw3, pixaux, bincount, accum);
    fill_bins<<<288, 256, 0, stream>>>(bincount, pixmask, idx, pixaux,
                                       tmask, tbase, ntiles);
    moe_sparse<<<MAXTILES, 256, 0, stream>>>(xT, idx, pixw3, tmask, tbase, ntiles,
        wbf, sb1, sb2, eb1, eb2, outT);
    final_add<<<1152, 256, 0, stream>>>(x, outT, pixaux, accum, out);
}